// Round 1
// baseline (112.872 us; speedup 1.0000x reference)
//
#include <hip/hip_runtime.h>
#include <math.h>

// Problem constants (B=8, P=64, V=32, N_TH1=30 -> D=1626)
#define NBP 512          // B*P
#define VV 32
#define DD 1626
#define DHALF 813        // directions per block (2 halves)

// Output layout (flat float32, concatenated in return order)
#define O_POINTS 0                         // (8,64*1626,3)  = 2497536
#define O_DIRH   2497536                   // (8,64,1626,4)  = 3330048
#define O_OVER   5827584                   // (8,64,1)       = 512
#define O_RETR   5828096                   // (8,64,1)       = 512
#define O_MEAN   5828608                   // (8,64,3)       = 1536
#define O_LOCAL  5830144                   // (8,64,32,3)    = 49152

#define L10_2 0.3010299956639812f    // log10(2)
#define L2_10 3.321928094887362f     // log2(10)
#define LH_MIN -66.43856189774725f   // log2(1e-20)

__device__ __forceinline__ float fexp2(float x) {
  return __builtin_amdgcn_exp2f(x);    // raw v_exp_f32
}

// inline direction via hardware v_sin/v_cos
__device__ __forceinline__ void make_dir_fast(int d, float& x, float& y, float& z) {
  if (d < 1624) {
    const int i1 = d / 58 + 1;        // 1..28
    const int i2 = d - (i1 - 1) * 58; // 0..57
    const float STEP = 0.10833078115826873f;        // pi/29
    const float th1 = -1.5707963267948966f + (float)i1 * STEP;
    const float th2 = -3.14159265358979323846f + (float)i2 * STEP;
    const float s1 = __sinf(th1);
    const float c1 = __cosf(th1);
    const float s2 = __sinf(th2);
    const float c2 = __cosf(th2);
    x = c1 * c2; y = c1 * s2; z = s1;
  } else if (d == 1624) {             // pole th1=-pi/2 (numpy f64->f32 values)
    x = -6.123234e-17f; y = -7.49880e-33f; z = -1.0f;
  } else {                            // pole th1=+pi/2
    x = -6.123234e-17f; y = -7.49880e-33f; z = 1.0f;
  }
}

// 3 waves/SIMD target: cap VGPR at 168 (demand ~150 without the w[] array)
__global__ __launch_bounds__(256, 3) void spt_kernel(
    const float* __restrict__ vertices,
    const float* __restrict__ smooth,
    float* __restrict__ out)
{
  const int bp   = blockIdx.x;   // 0..511
  const int half = blockIdx.y;   // 0..1
  const int tid  = threadIdx.x;

  __shared__ __align__(16) float slvx[VV];
  __shared__ __align__(16) float slvy[VV];
  __shared__ __align__(16) float slvz[VV];

  const int dbase = half * DHALF;

  // ---- wave-redundant mean via shuffle; lv -> LDS; ONE barrier ----
  const int v = tid & 31;
  const float* vp = vertices + bp * (VV * 3) + v * 3;
  const float vx = vp[0], vy = vp[1], vz = vp[2];
  float sx = vx, sy = vy, sz = vz;
#pragma unroll
  for (int m = 16; m >= 1; m >>= 1) {
    sx += __shfl_xor(sx, m);
    sy += __shfl_xor(sy, m);
    sz += __shfl_xor(sz, m);
  }
  const float mx = sx * (1.0f / 32.0f);
  const float my = sy * (1.0f / 32.0f);
  const float mz = sz * (1.0f / 32.0f);
  if (tid < VV) {
    slvx[tid] = vx - mx;
    slvy[tid] = vy - my;
    slvz[tid] = vz - mz;
  }
  __syncthreads();

  // ---- side outputs (once, by half 1) ----
  if (half == 1) {
    if (tid < VV * 3) {
      const int vv = tid / 3, c = tid - vv * 3;
      const float val = (c == 0) ? slvx[vv] : ((c == 1) ? slvy[vv] : slvz[vv]);
      out[O_LOCAL + bp * (VV * 3) + tid] = val;
    }
    if (tid == 96) {
      out[O_MEAN + bp * 3 + 0] = mx;
      out[O_MEAN + bp * 3 + 1] = my;
      out[O_MEAN + bp * 3 + 2] = mz;
      out[O_OVER + bp] = 0.f;
      out[O_RETR + bp] = 0.f;
    }
  }

  // ---- persist local_v in registers: read LDS ONCE (24 ds_read_b128),
  //      instead of 48 per direction (was ~153 per thread total) ----
  float lx[VV], ly[VV], lz[VV];
#pragma unroll
  for (int j = 0; j < VV / 4; j++) {
    const float4 X = ((const float4*)slvx)[j];
    const float4 Y = ((const float4*)slvy)[j];
    const float4 Z = ((const float4*)slvz)[j];
    lx[4*j+0] = X.x; lx[4*j+1] = X.y; lx[4*j+2] = X.z; lx[4*j+3] = X.w;
    ly[4*j+0] = Y.x; ly[4*j+1] = Y.y; ly[4*j+2] = Y.z; ly[4*j+3] = Y.w;
    lz[4*j+0] = Z.x; lz[4*j+1] = Z.y; lz[4*j+2] = Z.z; lz[4*j+3] = Z.w;
  }

  const float p     = smooth[bp];
  const float inv_p = 1.0f / p;
  const float pm1   = p - 1.0f;
  const float plt   = p * L10_2;

  auto process = [&](int idx) {
    const int d = dbase + idx;
    float dx, dy, dz;
    make_dir_fast(d, dx, dy, dz);

    // ---- pass 1: zmax only (z recomputed in pass 2, bitwise-identical expr;
    //      saves the 32-reg w[] array -> fits 3 waves/SIMD) ----
    float zm0 = 0.f, zm1 = 0.f, zm2 = 0.f, zm3 = 0.f;
#pragma unroll
    for (int j = 0; j < VV / 4; j++) {
      float z0 = fmaxf(fmaf(lx[4*j+0], dx, fmaf(ly[4*j+0], dy, lz[4*j+0] * dz)), 0.f);
      float z1 = fmaxf(fmaf(lx[4*j+1], dx, fmaf(ly[4*j+1], dy, lz[4*j+1] * dz)), 0.f);
      float z2 = fmaxf(fmaf(lx[4*j+2], dx, fmaf(ly[4*j+2], dy, lz[4*j+2] * dz)), 0.f);
      float z3 = fmaxf(fmaf(lx[4*j+3], dx, fmaf(ly[4*j+3], dy, lz[4*j+3] * dz)), 0.f);
      zm0 = fmaxf(zm0, z0); zm1 = fmaxf(zm1, z1);
      zm2 = fmaxf(zm2, z2); zm3 = fmaxf(zm3, z3);
    }
    const float zmax = fmaxf(fmaxf(zm0, zm1), fmaxf(zm2, zm3));

    // rescale exponent kc (zmax==0 -> log2=-inf -> kc=20)
    const float expo = __log2f(zmax) * plt;
    float kc = 0.f;
    if (expo < -20.f) {
      kc = fminf(fmaxf(ceilf((-15.f - expo) * inv_p), 0.f), 20.f);
    }
    const float kcl = kc * L2_10;      // log2(k)
    const float A   = p * kcl;         // exponent offset for w2

    // ---- pass 2 (old pass 3 FUSED in: C2 is scalar, factors out of the
    //      lv-weighted sum): w2 = 2^(pm1*log2(z)+A); s += w2*z; a += w2*lv ----
    float s0 = 0.f, s1 = 0.f, s2 = 0.f, s3 = 0.f;
    float ax = 0.f, ay = 0.f, az = 0.f;
#pragma unroll
    for (int j = 0; j < VV / 4; j++) {
      float z0 = fmaxf(fmaf(lx[4*j+0], dx, fmaf(ly[4*j+0], dy, lz[4*j+0] * dz)), 0.f);
      float z1 = fmaxf(fmaf(lx[4*j+1], dx, fmaf(ly[4*j+1], dy, lz[4*j+1] * dz)), 0.f);
      float z2 = fmaxf(fmaf(lx[4*j+2], dx, fmaf(ly[4*j+2], dy, lz[4*j+2] * dz)), 0.f);
      float z3 = fmaxf(fmaf(lx[4*j+3], dx, fmaf(ly[4*j+3], dy, lz[4*j+3] * dz)), 0.f);
      float w0 = fexp2(fmaf(pm1, __log2f(z0), A));   // zv=0 -> -inf -> 0
      float w1 = fexp2(fmaf(pm1, __log2f(z1), A));
      float w2 = fexp2(fmaf(pm1, __log2f(z2), A));
      float w3 = fexp2(fmaf(pm1, __log2f(z3), A));
      s0 += w0 * z0;  s1 += w1 * z1;
      s2 += w2 * z2;  s3 += w3 * z3;
      ax = fmaf(w0, lx[4*j+0], fmaf(w1, lx[4*j+1], fmaf(w2, lx[4*j+2], fmaf(w3, lx[4*j+3], ax))));
      ay = fmaf(w0, ly[4*j+0], fmaf(w1, ly[4*j+1], fmaf(w2, ly[4*j+2], fmaf(w3, ly[4*j+3], ay))));
      az = fmaf(w0, lz[4*j+0], fmaf(w1, lz[4*j+1], fmaf(w2, lz[4*j+2], fmaf(w3, lz[4*j+3], az))));
    }
    const float ssum = (s0 + s1) + (s2 + s3);

    float lh = LH_MIN;
    float C2 = 0.f;                    // dhdz_i = w2_i * C2
    if (ssum > 0.f) {
      lh = inv_p * __log2f(ssum);
      C2 = fexp2(-fmaf(pm1, lh, kcl));
    }

    const int pbase = bp * DD + d;
    out[O_POINTS + pbase * 3 + 0] = fmaf(C2, ax, mx);
    out[O_POINTS + pbase * 3 + 1] = fmaf(C2, ay, my);
    out[O_POINTS + pbase * 3 + 2] = fmaf(C2, az, mz);

    // direction_h row as one dwordx4 store (w = h/k)
    float4 dvh = make_float4(dx, dy, dz, fexp2(lh - kcl));
    ((float4*)(out + O_DIRH))[pbase] = dvh;
  };

  process(tid);
  process(256 + tid);
  process(512 + tid);
  if (tid < DHALF - 768) process(768 + tid);   // 45 threads
}

extern "C" void kernel_launch(void* const* d_in, const int* in_sizes, int n_in,
                              void* d_out, int out_size, void* d_ws, size_t ws_size,
                              hipStream_t stream) {
  const float* vertices = (const float*)d_in[0];  // (8,64,32,3) f32
  const float* smooth   = (const float*)d_in[1];  // (8,64) f32
  float* out = (float*)d_out;

  spt_kernel<<<dim3(NBP, 2), 256, 0, stream>>>(vertices, smooth, out);
}

// Round 2
// 107.509 us; speedup vs baseline: 1.0499x; 1.0499x over previous
//
#include <hip/hip_runtime.h>
#include <math.h>

// Problem constants (B=8, P=64, V=32, N_TH1=30 -> D=1626)
#define NBP 512          // B*P
#define VV 32
#define DD 1626
#define DHALF 813        // directions per block (2 halves)

// Output layout (flat float32, concatenated in return order)
#define O_POINTS 0                         // (8,64*1626,3)  = 2497536
#define O_DIRH   2497536                   // (8,64,1626,4)  = 3330048
#define O_OVER   5827584                   // (8,64,1)       = 512
#define O_RETR   5828096                   // (8,64,1)       = 512
#define O_MEAN   5828608                   // (8,64,3)       = 1536
#define O_LOCAL  5830144                   // (8,64,32,3)    = 49152

#define L10_2 0.3010299956639812f    // log10(2)
#define L2_10 3.321928094887362f     // log2(10)
#define LH_MIN -66.43856189774725f   // log2(1e-20)

__device__ __forceinline__ float fexp2(float x) {
  return __builtin_amdgcn_exp2f(x);    // raw v_exp_f32
}

// inline direction via hardware v_sin/v_cos
__device__ __forceinline__ void make_dir_fast(int d, float& x, float& y, float& z) {
  if (d < 1624) {
    const int i1 = d / 58 + 1;        // 1..28
    const int i2 = d - (i1 - 1) * 58; // 0..57
    const float STEP = 0.10833078115826873f;        // pi/29
    const float th1 = -1.5707963267948966f + (float)i1 * STEP;
    const float th2 = -3.14159265358979323846f + (float)i2 * STEP;
    const float s1 = __sinf(th1);
    const float c1 = __cosf(th1);
    const float s2 = __sinf(th2);
    const float c2 = __cosf(th2);
    x = c1 * c2; y = c1 * s2; z = s1;
  } else if (d == 1624) {             // pole th1=-pi/2 (numpy f64->f32 values)
    x = -6.123234e-17f; y = -7.49880e-33f; z = -1.0f;
  } else {                            // pole th1=+pi/2
    x = -6.123234e-17f; y = -7.49880e-33f; z = 1.0f;
  }
}

// z-chunk: identical expression/order to the passing round-1 kernel
#define ZCHUNK(X, Y, Z, z0, z1, z2, z3)                              \
  z0 = fmaxf(fmaf((X).x, dx, fmaf((Y).x, dy, (Z).x * dz)), 0.f);     \
  z1 = fmaxf(fmaf((X).y, dx, fmaf((Y).y, dy, (Z).y * dz)), 0.f);     \
  z2 = fmaxf(fmaf((X).z, dx, fmaf((Y).z, dy, (Z).z * dz)), 0.f);     \
  z3 = fmaxf(fmaf((X).w, dx, fmaf((Y).w, dy, (Z).w * dz)), 0.f);

// pass-1 chunk: running 4-lane max
#define P1CHUNK(X, Y, Z)                                             \
  { float z0, z1, z2, z3; ZCHUNK(X, Y, Z, z0, z1, z2, z3)            \
    zm0 = fmaxf(zm0, z0); zm1 = fmaxf(zm1, z1);                      \
    zm2 = fmaxf(zm2, z2); zm3 = fmaxf(zm3, z3); }

// pass-2 chunk: w2 = 2^(pm1*log2(z)+A); s += w2*z; a += w2*lv (fused dhdx)
#define P2CHUNK(X, Y, Z)                                             \
  { float z0, z1, z2, z3; ZCHUNK(X, Y, Z, z0, z1, z2, z3)            \
    float w0 = fexp2(fmaf(pm1, __log2f(z0), A));                     \
    float w1 = fexp2(fmaf(pm1, __log2f(z1), A));                     \
    float w2 = fexp2(fmaf(pm1, __log2f(z2), A));                     \
    float w3 = fexp2(fmaf(pm1, __log2f(z3), A));                     \
    s0 += w0 * z0;  s1 += w1 * z1;                                   \
    s2 += w2 * z2;  s3 += w3 * z3;                                   \
    ax = fmaf(w0, (X).x, fmaf(w1, (X).y, fmaf(w2, (X).z, fmaf(w3, (X).w, ax)))); \
    ay = fmaf(w0, (Y).x, fmaf(w1, (Y).y, fmaf(w2, (Y).z, fmaf(w3, (Y).w, ay)))); \
    az = fmaf(w0, (Z).x, fmaf(w1, (Z).y, fmaf(w2, (Z).z, fmaf(w3, (Z).w, az)))); }

// 3 waves/SIMD: cap VGPR at 168 (demand ~130 with named-register local_v)
__global__ __launch_bounds__(256, 3) void spt_kernel(
    const float* __restrict__ vertices,
    const float* __restrict__ smooth,
    float* __restrict__ out)
{
  const int bp   = blockIdx.x;   // 0..511
  const int half = blockIdx.y;   // 0..1
  const int tid  = threadIdx.x;

  __shared__ __align__(16) float slvx[VV];
  __shared__ __align__(16) float slvy[VV];
  __shared__ __align__(16) float slvz[VV];

  const int dbase = half * DHALF;

  // ---- wave-redundant mean via shuffle; lv -> LDS; ONE barrier ----
  const int v = tid & 31;
  const float* vp = vertices + bp * (VV * 3) + v * 3;
  const float vx = vp[0], vy = vp[1], vz = vp[2];
  float sx = vx, sy = vy, sz = vz;
#pragma unroll
  for (int m = 16; m >= 1; m >>= 1) {
    sx += __shfl_xor(sx, m);
    sy += __shfl_xor(sy, m);
    sz += __shfl_xor(sz, m);
  }
  const float mx = sx * (1.0f / 32.0f);
  const float my = sy * (1.0f / 32.0f);
  const float mz = sz * (1.0f / 32.0f);
  if (tid < VV) {
    slvx[tid] = vx - mx;
    slvy[tid] = vy - my;
    slvz[tid] = vz - mz;
  }
  __syncthreads();

  // ---- side outputs (once, by half 1) ----
  if (half == 1) {
    if (tid < VV * 3) {
      const int vv = tid / 3, c = tid - vv * 3;
      const float val = (c == 0) ? slvx[vv] : ((c == 1) ? slvy[vv] : slvz[vv]);
      out[O_LOCAL + bp * (VV * 3) + tid] = val;
    }
    if (tid == 96) {
      out[O_MEAN + bp * 3 + 0] = mx;
      out[O_MEAN + bp * 3 + 1] = my;
      out[O_MEAN + bp * 3 + 2] = mz;
      out[O_OVER + bp] = 0.f;
      out[O_RETR + bp] = 0.f;
    }
  }

  // ---- local_v in NAMED float4 registers (no arrays -> no scratch demotion;
  //      round-1's lambda-captured arrays were address-taken and spilled:
  //      VGPR=84, FETCH 52MB, WRITE 80MB of scratch traffic) ----
  const float4 X0 = ((const float4*)slvx)[0], X1 = ((const float4*)slvx)[1],
               X2 = ((const float4*)slvx)[2], X3 = ((const float4*)slvx)[3],
               X4 = ((const float4*)slvx)[4], X5 = ((const float4*)slvx)[5],
               X6 = ((const float4*)slvx)[6], X7 = ((const float4*)slvx)[7];
  const float4 Y0 = ((const float4*)slvy)[0], Y1 = ((const float4*)slvy)[1],
               Y2 = ((const float4*)slvy)[2], Y3 = ((const float4*)slvy)[3],
               Y4 = ((const float4*)slvy)[4], Y5 = ((const float4*)slvy)[5],
               Y6 = ((const float4*)slvy)[6], Y7 = ((const float4*)slvy)[7];
  const float4 Z0 = ((const float4*)slvz)[0], Z1 = ((const float4*)slvz)[1],
               Z2 = ((const float4*)slvz)[2], Z3 = ((const float4*)slvz)[3],
               Z4 = ((const float4*)slvz)[4], Z5 = ((const float4*)slvz)[5],
               Z6 = ((const float4*)slvz)[6], Z7 = ((const float4*)slvz)[7];

  const float p     = smooth[bp];
  const float inv_p = 1.0f / p;
  const float pm1   = p - 1.0f;
  const float plt   = p * L10_2;

#pragma unroll
  for (int it = 0; it < 4; ++it) {
    if (it == 3 && tid >= DHALF - 768) break;   // tail: only 45 threads
    const int idx = it * 256 + tid;
    const int d = dbase + idx;
    float dx, dy, dz;
    make_dir_fast(d, dx, dy, dz);

    // ---- pass 1: zmax ----
    float zm0 = 0.f, zm1 = 0.f, zm2 = 0.f, zm3 = 0.f;
    P1CHUNK(X0, Y0, Z0) P1CHUNK(X1, Y1, Z1)
    P1CHUNK(X2, Y2, Z2) P1CHUNK(X3, Y3, Z3)
    P1CHUNK(X4, Y4, Z4) P1CHUNK(X5, Y5, Z5)
    P1CHUNK(X6, Y6, Z6) P1CHUNK(X7, Y7, Z7)
    const float zmax = fmaxf(fmaxf(zm0, zm1), fmaxf(zm2, zm3));

    // rescale exponent kc (zmax==0 -> log2=-inf -> kc=20)
    const float expo = __log2f(zmax) * plt;
    float kc = 0.f;
    if (expo < -20.f) {
      kc = fminf(fmaxf(ceilf((-15.f - expo) * inv_p), 0.f), 20.f);
    }
    const float kcl = kc * L2_10;      // log2(k)
    const float A   = p * kcl;         // exponent offset for w2

    // ---- pass 2 (dhdx fused; C2 scalar factors out of lv-weighted sum) ----
    float s0 = 0.f, s1 = 0.f, s2 = 0.f, s3 = 0.f;
    float ax = 0.f, ay = 0.f, az = 0.f;
    P2CHUNK(X0, Y0, Z0) P2CHUNK(X1, Y1, Z1)
    P2CHUNK(X2, Y2, Z2) P2CHUNK(X3, Y3, Z3)
    P2CHUNK(X4, Y4, Z4) P2CHUNK(X5, Y5, Z5)
    P2CHUNK(X6, Y6, Z6) P2CHUNK(X7, Y7, Z7)
    const float ssum = (s0 + s1) + (s2 + s3);

    float lh = LH_MIN;
    float C2 = 0.f;                    // dhdz_i = w2_i * C2
    if (ssum > 0.f) {
      lh = inv_p * __log2f(ssum);
      C2 = fexp2(-fmaf(pm1, lh, kcl));
    }

    const int pbase = bp * DD + d;
    out[O_POINTS + pbase * 3 + 0] = fmaf(C2, ax, mx);
    out[O_POINTS + pbase * 3 + 1] = fmaf(C2, ay, my);
    out[O_POINTS + pbase * 3 + 2] = fmaf(C2, az, mz);

    // direction_h row as one dwordx4 store (w = h/k)
    float4 dvh = make_float4(dx, dy, dz, fexp2(lh - kcl));
    ((float4*)(out + O_DIRH))[pbase] = dvh;
  }
}

extern "C" void kernel_launch(void* const* d_in, const int* in_sizes, int n_in,
                              void* d_out, int out_size, void* d_ws, size_t ws_size,
                              hipStream_t stream) {
  const float* vertices = (const float*)d_in[0];  // (8,64,32,3) f32
  const float* smooth   = (const float*)d_in[1];  // (8,64) f32
  float* out = (float*)d_out;

  spt_kernel<<<dim3(NBP, 2), 256, 0, stream>>>(vertices, smooth, out);
}